// Round 9
// baseline (36.335 us; speedup 1.0000x reference)
//
#include <hip/hip_runtime.h>
#include <math.h>

#define NQ 4
#define NL 2
#define INF 8
#define OUTF 128
#define K2_BLOCKS 512
#define K2_WAVES (K2_BLOCKS * 4)         // 2048 waves
#define ROWS_PER_SWEEP (2 * K2_WAVES)    // 4096 rows per iteration

typedef float fv4 __attribute__((ext_vector_type(4)));
typedef int   iv4 __attribute__((ext_vector_type(4)));

__device__ __forceinline__ float fast_tanh(float x) {
    float e = __expf(2.0f * x);
    return 1.0f - 2.0f / (e + 1.0f);
}

// ---------------- K1: one thread = one row; z[row][0..3] -> zout ----------
__global__ __launch_bounds__(256) void zcalc_kernel(
    const float* __restrict__ x,       // [B,8]
    const float* __restrict__ W_pre,   // [4,8]
    const float* __restrict__ b_pre,   // [4]
    const float* __restrict__ theta,   // [2,4]
    float* __restrict__ zout,          // [B,4] (workspace)
    int B)
{
    const int row = blockIdx.x * 256 + threadIdx.x;
    if (row >= B) return;

    const float4* xr = reinterpret_cast<const float4*>(x + (size_t)row * INF);
    const float4 xa = xr[0], xb = xr[1];

    float ca[NQ], sa[NQ];
    #pragma unroll
    for (int w = 0; w < NQ; ++w) {
        const float* wp = W_pre + w * INF;
        float acc = b_pre[w];
        acc += xa.x * wp[0] + xa.y * wp[1] + xa.z * wp[2] + xa.w * wp[3];
        acc += xb.x * wp[4] + xb.y * wp[5] + xb.z * wp[6] + xb.w * wp[7];
        float alpha = 3.14159265358979323846f * fast_tanh(acc);
        __sincosf(0.5f * alpha, &sa[w], &ca[w]);
    }

    float ct[NL][NQ], st_[NL][NQ];
    #pragma unroll
    for (int l = 0; l < NL; ++l)
        #pragma unroll
        for (int w = 0; w < NQ; ++w)
            __sincosf(0.5f * theta[l * NQ + w], &st_[l][w], &ct[l][w]);

    float st[16];
    #pragma unroll
    for (int i = 0; i < 16; ++i) {
        float v = (i & 8) ? sa[0] : ca[0];
        v *= (i & 4) ? sa[1] : ca[1];
        v *= (i & 2) ? sa[2] : ca[2];
        v *= (i & 1) ? sa[3] : ca[3];
        st[i] = v;
    }

    #pragma unroll
    for (int l = 0; l < NL; ++l) {
        #pragma unroll
        for (int w = 0; w < NQ; ++w) {
            const float c = ct[l][w], s = st_[l][w];
            const int bit = 8 >> w;
            #pragma unroll
            for (int i = 0; i < 16; ++i) {
                if (!(i & bit)) {
                    const int j = i | bit;
                    float a0 = st[i], a1 = st[j];
                    st[i] = c * a0 - s * a1;
                    st[j] = s * a0 + c * a1;
                }
            }
        }
        #pragma unroll
        for (int w = 0; w < NQ - 1; ++w) {
            const int cb = 8 >> w, tb = 8 >> (w + 1);
            #pragma unroll
            for (int i = 0; i < 16; ++i) {
                if ((i & cb) && !(i & tb)) {
                    const int j = i | tb;
                    float t = st[i]; st[i] = st[j]; st[j] = t;
                }
            }
        }
    }

    float p[16];
    #pragma unroll
    for (int i = 0; i < 16; ++i) p[i] = st[i] * st[i];

    float z[NQ];
    #pragma unroll
    for (int w = 0; w < NQ; ++w) {
        const int bit = 8 >> w;
        float zp = 0.f, zm = 0.f;
        #pragma unroll
        for (int i = 0; i < 16; ++i) {
            if (i & bit) zm += p[i]; else zp += p[i];
        }
        z[w] = zp - zm;
    }

    *reinterpret_cast<float4*>(zout + (size_t)row * 4) =
        make_float4(z[0], z[1], z[2], z[3]);
}

// ---------------- K2: fill-like expansion, scalar z path ------------------
// Per wave per iteration: ONE scalar 32B z fetch (lgkmcnt pipe) + ONE
// global_store_dwordx4 per lane (1KiB/wave). NO vmcnt waits in the loop ->
// store queue free-flows at full depth, like the 6.6 TB/s fill kernel.
struct ZPair { iv4 lo, hi; };

__device__ __forceinline__ ZPair sload_zpair(const float* z, size_t rp) {
    ZPair r;
    unsigned long long a = (unsigned long long)(const void*)z + rp * 32ull;
    asm volatile("s_load_dwordx4 %0, %2, 0x0\n\t"
                 "s_load_dwordx4 %1, %2, 0x10"
                 : "=&s"(r.lo), "=&s"(r.hi) : "s"(a));
    return r;
}
__device__ __forceinline__ void swait_zpair(ZPair& p) {
    // waits the (single) outstanding s_load pair; "+s" ties consumers after
    asm volatile("s_waitcnt lgkmcnt(0)" : "+s"(p.lo), "+s"(p.hi) :: "memory");
}

__global__ __launch_bounds__(256) void expand_kernel(
    const float* __restrict__ z,       // [B,4] (workspace)
    const float* __restrict__ W_post,  // [128,4]
    const float* __restrict__ b_post,  // [128]
    float* __restrict__ out,           // [B,128]
    int B, int iters)
{
    const int lane  = threadIdx.x & 63;
    const int wv    = __builtin_amdgcn_readfirstlane(threadIdx.x >> 6);
    const int g     = blockIdx.x * 4 + wv;          // global wave id (SGPR)
    const int colb  = (lane & 31) * 4;
    const int rhalf = lane >> 5;

    const float4 w0 = *reinterpret_cast<const float4*>(W_post + (colb + 0) * NQ);
    const float4 w1 = *reinterpret_cast<const float4*>(W_post + (colb + 1) * NQ);
    const float4 w2 = *reinterpret_cast<const float4*>(W_post + (colb + 2) * NQ);
    const float4 w3 = *reinterpret_cast<const float4*>(W_post + (colb + 3) * NQ);
    const float4 bp = *reinterpret_cast<const float4*>(b_post + colb);

    float* optr = out + ((size_t)2 * g + rhalf) * OUTF + colb;
    const size_t OSTEP = (size_t)ROWS_PER_SWEEP * OUTF;   // floats per sweep

    #define COMPUTE_STORE(P)                                                   \
    {                                                                          \
        float4 zv;                                                             \
        zv.x = rhalf ? __int_as_float((P).hi.x) : __int_as_float((P).lo.x);    \
        zv.y = rhalf ? __int_as_float((P).hi.y) : __int_as_float((P).lo.y);    \
        zv.z = rhalf ? __int_as_float((P).hi.z) : __int_as_float((P).lo.z);    \
        zv.w = rhalf ? __int_as_float((P).hi.w) : __int_as_float((P).lo.w);    \
        fv4 o;                                                                 \
        o.x = fmaf(zv.w, w0.w, fmaf(zv.z, w0.z, fmaf(zv.y, w0.y, fmaf(zv.x, w0.x, bp.x)))); \
        o.y = fmaf(zv.w, w1.w, fmaf(zv.z, w1.z, fmaf(zv.y, w1.y, fmaf(zv.x, w1.x, bp.y)))); \
        o.z = fmaf(zv.w, w2.w, fmaf(zv.z, w2.z, fmaf(zv.y, w2.y, fmaf(zv.x, w2.x, bp.z)))); \
        o.w = fmaf(zv.w, w3.w, fmaf(zv.z, w3.z, fmaf(zv.y, w3.y, fmaf(zv.x, w3.x, bp.w)))); \
        *reinterpret_cast<fv4*>(optr) = o;                                     \
        optr += OSTEP;                                                         \
    }

    if (iters > 0) {
        ZPair zc = sload_zpair(z, (size_t)g);
        int i = 0;
        while (true) {
            // iter i consumes zc
            swait_zpair(zc);
            const bool hn = (i + 1) < iters;
            ZPair zn;
            if (hn) zn = sload_zpair(z, (size_t)(i + 1) * K2_WAVES + g);
            COMPUTE_STORE(zc);
            ++i;
            if (!hn) break;
            // iter i consumes zn
            swait_zpair(zn);
            const bool hn2 = (i + 1) < iters;
            if (hn2) zc = sload_zpair(z, (size_t)(i + 1) * K2_WAVES + g);
            COMPUTE_STORE(zn);
            ++i;
            if (!hn2) break;
        }
    }

    // tail: rows [iters*ROWS_PER_SWEEP, B) — one guarded row-pair per wave
    const int trow = iters * ROWS_PER_SWEEP + 2 * g + rhalf;
    if (trow < B) {
        const float4 zt = *reinterpret_cast<const float4*>(z + (size_t)trow * 4);
        float4 o;
        o.x = fmaf(zt.w, w0.w, fmaf(zt.z, w0.z, fmaf(zt.y, w0.y, fmaf(zt.x, w0.x, bp.x))));
        o.y = fmaf(zt.w, w1.w, fmaf(zt.z, w1.z, fmaf(zt.y, w1.y, fmaf(zt.x, w1.x, bp.y))));
        o.z = fmaf(zt.w, w2.w, fmaf(zt.z, w2.z, fmaf(zt.y, w2.y, fmaf(zt.x, w2.x, bp.z))));
        o.w = fmaf(zt.w, w3.w, fmaf(zt.z, w3.z, fmaf(zt.y, w3.y, fmaf(zt.x, w3.x, bp.w))));
        *reinterpret_cast<float4*>(out + (size_t)trow * OUTF + colb) = o;
    }
    #undef COMPUTE_STORE
}

extern "C" void kernel_launch(void* const* d_in, const int* in_sizes, int n_in,
                              void* d_out, int out_size, void* d_ws, size_t ws_size,
                              hipStream_t stream) {
    const float* x      = (const float*)d_in[0];
    const float* W_pre  = (const float*)d_in[1];
    const float* b_pre  = (const float*)d_in[2];
    const float* theta  = (const float*)d_in[3];
    const float* W_post = (const float*)d_in[4];
    const float* b_post = (const float*)d_in[5];
    float* out  = (float*)d_out;
    float* zbuf = (float*)d_ws;   // B*4 floats

    const int B = in_sizes[0] / INF;

    const int k1_blocks = (B + 255) / 256;
    zcalc_kernel<<<dim3(k1_blocks), dim3(256), 0, stream>>>(
        x, W_pre, b_pre, theta, zbuf, B);

    const int iters = B / ROWS_PER_SWEEP;
    expand_kernel<<<dim3(K2_BLOCKS), dim3(256), 0, stream>>>(
        zbuf, W_post, b_post, out, B, iters);
}

// Round 10
// 27.504 us; speedup vs baseline: 1.3211x; 1.3211x over previous
//
#include <hip/hip_runtime.h>
#include <math.h>

#define NQ 4
#define NL 2
#define INF 8
#define OUTF 128

typedef float fv4 __attribute__((ext_vector_type(4)));

__device__ __forceinline__ float fast_tanh(float x) {
    float e = __expf(2.0f * x);
    return 1.0f - 2.0f / (e + 1.0f);
}

__global__ __launch_bounds__(256) void tq_kernel(
    const float* __restrict__ x,       // [B,8]
    const float* __restrict__ W_pre,   // [4,8]
    const float* __restrict__ b_pre,   // [4]
    const float* __restrict__ theta,   // [2,4]
    const float* __restrict__ W_post,  // [128,4]
    const float* __restrict__ b_post,  // [128]
    float* __restrict__ out,           // [B,128]
    int B)
{
    const int tid = threadIdx.x;
    const int row = blockIdx.x * 256 + tid;

    __shared__ float zsh[256][4];

    if (row < B) {
        // ---- phase 1: embedding angles ----
        const float4* xr = reinterpret_cast<const float4*>(x + (size_t)row * INF);
        float4 xa = xr[0];
        float4 xb = xr[1];

        float ca[NQ], sa[NQ];
        #pragma unroll
        for (int w = 0; w < NQ; ++w) {
            const float* wp = W_pre + w * INF;   // wave-uniform -> scalar loads
            float acc = b_pre[w];
            acc += xa.x * wp[0] + xa.y * wp[1] + xa.z * wp[2] + xa.w * wp[3];
            acc += xb.x * wp[4] + xb.y * wp[5] + xb.z * wp[6] + xb.w * wp[7];
            float alpha = 3.14159265358979323846f * fast_tanh(acc);
            __sincosf(0.5f * alpha, &sa[w], &ca[w]);
        }

        float ct[NL][NQ], st_[NL][NQ];
        #pragma unroll
        for (int l = 0; l < NL; ++l)
            #pragma unroll
            for (int w = 0; w < NQ; ++w)
                __sincosf(0.5f * theta[l * NQ + w], &st_[l][w], &ct[l][w]);

        // ---- phase 2: statevector sim (wire w <-> bit mask 8>>w) ----
        float st[16];
        #pragma unroll
        for (int i = 0; i < 16; ++i) {
            float v = (i & 8) ? sa[0] : ca[0];
            v *= (i & 4) ? sa[1] : ca[1];
            v *= (i & 2) ? sa[2] : ca[2];
            v *= (i & 1) ? sa[3] : ca[3];
            st[i] = v;
        }

        #pragma unroll
        for (int l = 0; l < NL; ++l) {
            #pragma unroll
            for (int w = 0; w < NQ; ++w) {
                const float c = ct[l][w], s = st_[l][w];
                const int bit = 8 >> w;
                #pragma unroll
                for (int i = 0; i < 16; ++i) {
                    if (!(i & bit)) {
                        const int j = i | bit;
                        float a0 = st[i], a1 = st[j];
                        st[i] = c * a0 - s * a1;
                        st[j] = s * a0 + c * a1;
                    }
                }
            }
            #pragma unroll
            for (int w = 0; w < NQ - 1; ++w) {
                const int cb = 8 >> w, tb = 8 >> (w + 1);
                #pragma unroll
                for (int i = 0; i < 16; ++i) {
                    if ((i & cb) && !(i & tb)) {
                        const int j = i | tb;
                        float t = st[i]; st[i] = st[j]; st[j] = t;
                    }
                }
            }
        }

        // ---- phase 3: PauliZ expectations ----
        float p[16];
        #pragma unroll
        for (int i = 0; i < 16; ++i) p[i] = st[i] * st[i];

        #pragma unroll
        for (int w = 0; w < NQ; ++w) {
            const int bit = 8 >> w;
            float zp = 0.f, zm = 0.f;
            #pragma unroll
            for (int i = 0; i < 16; ++i) {
                if (i & bit) zm += p[i]; else zp += p[i];
            }
            zsh[tid][w] = zp - zm;
        }
    }
    __syncthreads();

    // ---- phase 4: pure-burst epilogue ----
    // Prefetch z for 16 rows into registers, THEN issue 16 stores with no
    // interleaved lgkmcnt waits (fill-style pure store stream). Two halves.
    const int lane  = tid & 63;
    const int wv    = tid >> 6;
    const int colb  = (lane & 31) * 4;   // column block [colb, colb+3]
    const int rhalf = lane >> 5;         // 0 or 1: which of the 2 rows/iter

    const float4 w0 = *reinterpret_cast<const float4*>(W_post + (colb + 0) * NQ);
    const float4 w1 = *reinterpret_cast<const float4*>(W_post + (colb + 1) * NQ);
    const float4 w2 = *reinterpret_cast<const float4*>(W_post + (colb + 2) * NQ);
    const float4 w3 = *reinterpret_cast<const float4*>(W_post + (colb + 3) * NQ);
    const float4 bp = *reinterpret_cast<const float4*>(b_post + colb);

    const int lr0   = wv * 64 + rhalf;
    const int rbase = blockIdx.x * 256 + wv * 64 + rhalf;

    if (rbase + 62 < B) {
        fv4* optr = reinterpret_cast<fv4*>(out + (size_t)rbase * OUTF + colb);
        #pragma unroll
        for (int h = 0; h < 2; ++h) {
            float4 zreg[16];
            #pragma unroll
            for (int r = 0; r < 16; ++r)
                zreg[r] = *reinterpret_cast<const float4*>(&zsh[lr0 + 2 * (16 * h + r)][0]);
            #pragma unroll
            for (int r = 0; r < 16; ++r) {
                const float4 z = zreg[r];
                fv4 o;
                o.x = fmaf(z.w, w0.w, fmaf(z.z, w0.z, fmaf(z.y, w0.y, fmaf(z.x, w0.x, bp.x))));
                o.y = fmaf(z.w, w1.w, fmaf(z.z, w1.z, fmaf(z.y, w1.y, fmaf(z.x, w1.x, bp.y))));
                o.z = fmaf(z.w, w2.w, fmaf(z.z, w2.z, fmaf(z.y, w2.y, fmaf(z.x, w2.x, bp.z))));
                o.w = fmaf(z.w, w3.w, fmaf(z.z, w3.z, fmaf(z.y, w3.y, fmaf(z.x, w3.x, bp.w))));
                optr[(size_t)2 * (16 * h + r) * (OUTF / 4)] = o;
            }
        }
    } else {
        for (int r = 0; r < 32; ++r) {
            const int rr = rbase + 2 * r;
            if (rr >= B) break;
            const int lr = lr0 + 2 * r;
            const float4 z = *reinterpret_cast<const float4*>(&zsh[lr][0]);
            float4 o;
            o.x = fmaf(z.w, w0.w, fmaf(z.z, w0.z, fmaf(z.y, w0.y, fmaf(z.x, w0.x, bp.x))));
            o.y = fmaf(z.w, w1.w, fmaf(z.z, w1.z, fmaf(z.y, w1.y, fmaf(z.x, w1.x, bp.y))));
            o.z = fmaf(z.w, w2.w, fmaf(z.z, w2.z, fmaf(z.y, w2.y, fmaf(z.x, w2.x, bp.z))));
            o.w = fmaf(z.w, w3.w, fmaf(z.z, w3.z, fmaf(z.y, w3.y, fmaf(z.x, w3.x, bp.w))));
            *reinterpret_cast<float4*>(out + (size_t)rr * OUTF + colb) = o;
        }
    }
}

extern "C" void kernel_launch(void* const* d_in, const int* in_sizes, int n_in,
                              void* d_out, int out_size, void* d_ws, size_t ws_size,
                              hipStream_t stream) {
    const float* x      = (const float*)d_in[0];
    const float* W_pre  = (const float*)d_in[1];
    const float* b_pre  = (const float*)d_in[2];
    const float* theta  = (const float*)d_in[3];
    const float* W_post = (const float*)d_in[4];
    const float* b_post = (const float*)d_in[5];
    float* out = (float*)d_out;

    const int B = in_sizes[0] / INF;
    const int nblocks = (B + 255) / 256;
    tq_kernel<<<dim3(nblocks), dim3(256), 0, stream>>>(
        x, W_pre, b_pre, theta, W_post, b_post, out, B);
}